// Round 6
// baseline (55765.796 us; speedup 1.0000x reference)
//
#include <hip/hip_runtime.h>

// ---------------------------------------------------------------------------
// 2-layer LSTM (B=16, L=2048, H=1024), one persistent scan kernel.
// Round-3 design (3rd resubmit; benches never ran - GPU acquisition
// timeouts): tag-fused h publish. Each published u64 = {2 x fp16 h, u32 step
// tag} (8B atomic => single-copy atomic, no tearing). The consumer's polling
// load IS the data load: removes producer vmcnt(0) ack wait, separate flag
// store, and post-detect data load (4 coherence round-trips -> ~1.5).
// Double-buffered by step parity, equality poll (tag == s).
// Also: ONE __syncthreads per step (phase B+C fused into wave 0; acc_s
// double-buffered by parity so waves 1-7 may run one step ahead).
// ---------------------------------------------------------------------------

typedef _Float16 half8 __attribute__((ext_vector_type(8)));
typedef float    float4v __attribute__((ext_vector_type(4)));
typedef unsigned long long u64;
typedef unsigned u32;

#define NBLK 256
#define NTHR 512
#define BB   16
#define LL   2048
#define HH   1024
#define KK   2048      // concat K (x-part 1024 + h-part 1024)
#define NJ   4         // h columns per block
#define NR   16        // gate rows per block (4 gates * NJ)
#define NSTEP 4096     // 2 layers * L

// ws layout (bytes)
#define WS_XT16   0u              // [L][B][H] fp16 : 64 MiB
#define WS_H1SEQ  67108864u       // [L][B][H] fp16 : 64 MiB
#define WS_HPUB   134217728u      // [2][B][256][2] u64 : 128 KiB

struct ScanParams {
  const float* W[4];     // Wf,Wi,Wo,Wc  [2][H][H]
  const float* U[4];     // Uf,Ui,Uo,Uc  [2][H][H]
  const float* bias4[4]; // bf,bi,bo,bc  [2][H]
  const _Float16* xT;    // [L][B][H]
  _Float16* h1seq;       // [L][B][H]
  u64* hpub;             // [2][B][256][2]  {h2i,h2i+1,tag}
  float* dout;           // [B][L][H]
};

// x [B][L][H] fp32 -> xT [L][B][H] fp16
__global__ void prep_convert(const float* __restrict__ x, _Float16* __restrict__ xT) {
  size_t id = (size_t)blockIdx.x * blockDim.x + threadIdx.x;   // 4,194,304 total
  int k8 = (int)(id & (HH / 8 - 1)) * 8;
  size_t bt = id >> 7;                 // b*L + t
  int b = (int)(bt >> 11);
  int t = (int)(bt & (LL - 1));
  const float* src = x + (bt << 10) + k8;
  float4v v0 = *(const float4v*)(src);
  float4v v1 = *(const float4v*)(src + 4);
  half8 o;
  o[0] = (_Float16)v0[0]; o[1] = (_Float16)v0[1]; o[2] = (_Float16)v0[2]; o[3] = (_Float16)v0[3];
  o[4] = (_Float16)v1[0]; o[5] = (_Float16)v1[1]; o[6] = (_Float16)v1[2]; o[7] = (_Float16)v1[3];
  *(half8*)(xT + (((size_t)t * BB + b) << 10) + k8) = o;
}

// zero hpub (tags 0 == "initial h", h = 0)
__global__ void prep_init(u64* hpub) {
  int i = blockIdx.x * blockDim.x + threadIdx.x;
  if (i < 2 * BB * 256 * 2) hpub[i] = 0ull;
}

__device__ __forceinline__ float sigm(float x) { return 1.f / (1.f + __expf(-x)); }
__device__ __forceinline__ float tanh_fast(float x) { return 1.f - 2.f / (1.f + __expf(2.f * x)); }

__global__ __launch_bounds__(NTHR, 2) void lstm_scan(ScanParams p) {
  __shared__ _Float16 wlds[2][NR][KK];     // 131072 B, persistent weights
  __shared__ float acc_s[2][8][16][17];    // parity-double-buffered partials
  __shared__ float bias_s[2][NR];

  const int tid  = threadIdx.x;
  const int blk  = blockIdx.x;
  const int wv   = tid >> 6;
  const int lane = tid & 63;
  const int frow = lane & 15;   // A: batch row ; B: gate row
  const int kgrp = lane >> 4;

  // ---- one-time: weights fp32 -> fp16 into LDS, XOR-swizzled rows ----
  for (int idx = tid; idx < 2 * NR * KK; idx += NTHR) {
    int l = idx >> 15;
    int r = (idx >> 11) & (NR - 1);      // r = q*4 + jj
    int k = idx & (KK - 1);
    int q = r >> 2, jj = r & 3;
    int j = blk * NJ + jj;
    float v;
    if (k < HH) v = p.W[q][((size_t)l * HH + j) * HH + k];
    else        v = p.U[q][((size_t)l * HH + j) * HH + (k - HH)];
    unsigned bo = ((unsigned)(k * 2)) ^ ((unsigned)((r & 7) << 4));
    *(_Float16*)((char*)&wlds[l][r][0] + bo) = (_Float16)v;
  }
  if (tid < 2 * NR) {
    int l = tid >> 4, r = tid & 15;
    bias_s[l][r] = p.bias4[r >> 2][l * HH + blk * NJ + (r & 3)];
  }
  // wave 0: lane -> cell (b = lane>>2, jj = lane&3); c-state in register
  float cst = 0.f;
  __syncthreads();

  for (int s = 0; s < NSTEP; ++s) {
    const int l   = s >> 11;
    const int t   = s & (LL - 1);
    const int par = s & 1;

    // ---- phase A ----
    half8 aop[8];
    if (wv < 4) {
      // x-part: no wait -> overlaps the h-wave poll and wave-0 tail
      const _Float16* inp = (l == 0) ? p.xT : p.h1seq;
      const _Float16* ab = inp + (size_t)t * (BB * HH) + frow * HH + wv * 256 + kgrp * 8;
#pragma unroll
      for (int kk = 0; kk < 8; ++kk)
        aop[kk] = *(const half8*)(ab + kk * 32);
    } else {
      // tag-fused poll: load 32 u64 {h,h,tag}; retry (per-lane) until all
      // tags == s. Data arrives with the successful poll -- no extra hop.
      const int hw = wv - 4;
      const u64* hp = p.hpub + (size_t)par * (BB * 256 * 2);
      const u32 want = (u32)s;
      const int qb = frow * 512 + hw * 128 + kgrp * 4;
      u64 q[32];
      bool ok = false;
      while (!ok) {
#pragma unroll
        for (int kk = 0; kk < 8; ++kk) {
#pragma unroll
          for (int j = 0; j < 4; ++j)
            q[kk * 4 + j] = __hip_atomic_load(hp + qb + kk * 16 + j,
                                              __ATOMIC_RELAXED, __HIP_MEMORY_SCOPE_AGENT);
        }
        ok = true;
#pragma unroll
        for (int i = 0; i < 32; ++i) ok &= ((u32)(q[i] >> 32) == want);
        if (!ok) __builtin_amdgcn_s_sleep(1);
      }
#pragma unroll
      for (int kk = 0; kk < 8; ++kk) {
        union { u32 w[4]; half8 v; } u;
        u.w[0] = (u32)q[kk * 4 + 0]; u.w[1] = (u32)q[kk * 4 + 1];
        u.w[2] = (u32)q[kk * 4 + 2]; u.w[3] = (u32)q[kk * 4 + 3];
        aop[kk] = u.v;
      }
    }

    const int kw0 = wv * 256 + kgrp * 8;
    const char* wrow = (const char*)&wlds[l][frow][0];
    half8 bop[8];
#pragma unroll
    for (int kk = 0; kk < 8; ++kk) {
      unsigned bo = (unsigned)((kw0 + kk * 32) * 2) ^ ((unsigned)((frow & 7) << 4));
      bop[kk] = *(const half8*)(wrow + bo);
    }
    float4v a0 = {0.f, 0.f, 0.f, 0.f}, a1 = {0.f, 0.f, 0.f, 0.f};
#pragma unroll
    for (int kk = 0; kk < 8; kk += 2) {
      a0 = __builtin_amdgcn_mfma_f32_16x16x32_f16(aop[kk],     bop[kk],     a0, 0, 0, 0);
      a1 = __builtin_amdgcn_mfma_f32_16x16x32_f16(aop[kk + 1], bop[kk + 1], a1, 0, 0, 0);
    }
    a0 += a1;
#pragma unroll
    for (int v = 0; v < 4; ++v)
      acc_s[par][wv][kgrp * 4 + v][frow] = a0[v];   // row=batch=(lane>>4)*4+v, col=gaterow
    __syncthreads();   // the ONLY barrier per step

    // ---- phase B+C fused: wave 0 reduces, runs the cell, publishes ----
    if (wv == 0) {
      const int b = lane >> 2, jj = lane & 3;
      float g0 = bias_s[l][jj],      g1 = bias_s[l][4 + jj];
      float g2 = bias_s[l][8 + jj],  g3 = bias_s[l][12 + jj];
#pragma unroll
      for (int w = 0; w < 8; ++w) {
        g0 += acc_s[par][w][b][jj];
        g1 += acc_s[par][w][b][4 + jj];
        g2 += acc_s[par][w][b][8 + jj];
        g3 += acc_s[par][w][b][12 + jj];
      }
      float f = sigm(g0), i = sigm(g1), o = sigm(g2), cc = tanh_fast(g3);
      cst = f * cst + i * cc;
      float hf = o * tanh_fast(cst);

      union { _Float16 h; unsigned short us; } cv; cv.h = (_Float16)hf;
      u32 hu = cv.us;
      u32 v1 = __shfl_xor(hu, 1);
      u32 v2 = __shfl_xor(hu, 2);
      u32 v3 = __shfl_xor(v1, 2);
      float f1 = __shfl_xor(hf, 1);
      float f2 = __shfl_xor(hf, 2);
      float f3 = __shfl_xor(f1, 2);
      if (jj == 0) {
        u32 pair01 = hu | (v1 << 16);
        u32 pair23 = v2 | (v3 << 16);
        u64 tagw = ((u64)(u32)(s + 1)) << 32;
        u64* dst = p.hpub + (size_t)((s + 1) & 1) * (BB * 256 * 2) + b * 512 + blk * 2;
        __hip_atomic_store(dst + 0, (u64)pair01 | tagw, __ATOMIC_RELAXED, __HIP_MEMORY_SCOPE_AGENT);
        __hip_atomic_store(dst + 1, (u64)pair23 | tagw, __ATOMIC_RELAXED, __HIP_MEMORY_SCOPE_AGENT);
        if (l == 0) {
          u64 hq = (u64)pair01 | ((u64)pair23 << 32);
          __hip_atomic_store((u64*)(p.h1seq + ((size_t)t * BB + b) * HH + blk * 4), hq,
                             __ATOMIC_RELAXED, __HIP_MEMORY_SCOPE_AGENT);
        } else {
          float4v ov; ov[0] = hf; ov[1] = f1; ov[2] = f2; ov[3] = f3;
          *(float4v*)(p.dout + ((size_t)b * LL + t) * HH + blk * 4) = ov;
        }
      }
    }
    // no second barrier: waves 1-7 run step s+1 phase A into acc_s[par^1],
    // never touching acc_s[par] (read by wave 0) until after barrier s+1.
  }
}

extern "C" void kernel_launch(void* const* d_in, const int* in_sizes, int n_in,
                              void* d_out, int out_size, void* d_ws, size_t ws_size,
                              hipStream_t stream) {
  const float* x = (const float*)d_in[0];
  ScanParams sp;
  sp.W[0] = (const float*)d_in[1]; sp.U[0] = (const float*)d_in[2];   // f
  sp.W[1] = (const float*)d_in[3]; sp.U[1] = (const float*)d_in[4];   // i
  sp.W[2] = (const float*)d_in[5]; sp.U[2] = (const float*)d_in[6];   // o
  sp.W[3] = (const float*)d_in[7]; sp.U[3] = (const float*)d_in[8];   // c
  sp.bias4[0] = (const float*)d_in[9];  sp.bias4[1] = (const float*)d_in[10];
  sp.bias4[2] = (const float*)d_in[11]; sp.bias4[3] = (const float*)d_in[12];

  char* ws = (char*)d_ws;
  sp.xT    = (const _Float16*)(ws + WS_XT16);
  sp.h1seq = (_Float16*)(ws + WS_H1SEQ);
  sp.hpub  = (u64*)(ws + WS_HPUB);
  sp.dout  = (float*)d_out;

  prep_convert<<<16384, 256, 0, stream>>>(x, (_Float16*)(ws + WS_XT16));
  prep_init<<<64, 256, 0, stream>>>((u64*)(ws + WS_HPUB));
  lstm_scan<<<NBLK, NTHR, 0, stream>>>(sp);
}

// Round 8
// 45752.295 us; speedup vs baseline: 1.2189x; 1.2189x over previous
//
#include <hip/hip_runtime.h>

// ---------------------------------------------------------------------------
// 2-layer LSTM (B=16, L=2048, H=1024), one persistent scan kernel.
// Round-7 design (resubmit; bench never ran - GPU acquisition timeout):
// CONVERGENT tag poll. Round-6 showed the all-words-repoll was a
// coherence-point flood (FETCH 1.2->5.9 GB, 55.8 ms, jitter to 88 ms): every
// failed round re-loaded the whole 64 KB parity buffer per block with
// L2-bypassing atomic loads, queueing ahead of producers' publishes.
// Fix: per-lane 32-bit done-mask; a word whose tag matched is NEVER reloaded.
// First pass = 32 pipelined loads; retries touch only straggler words.
// Tag-fusion itself is kept: u64 = {2 x fp16 h, u32 step tag}, detect IS the
// data delivery (no producer vmcnt ack, no separate flag, 1 barrier/step).
// ---------------------------------------------------------------------------

typedef _Float16 half8 __attribute__((ext_vector_type(8)));
typedef float    float4v __attribute__((ext_vector_type(4)));
typedef unsigned long long u64;
typedef unsigned u32;

#define NBLK 256
#define NTHR 512
#define BB   16
#define LL   2048
#define HH   1024
#define KK   2048      // concat K (x-part 1024 + h-part 1024)
#define NJ   4         // h columns per block
#define NR   16        // gate rows per block (4 gates * NJ)
#define NSTEP 4096     // 2 layers * L

// ws layout (bytes)
#define WS_XT16   0u              // [L][B][H] fp16 : 64 MiB
#define WS_H1SEQ  67108864u       // [L][B][H] fp16 : 64 MiB
#define WS_HPUB   134217728u      // [2][B][256][2] u64 : 128 KiB

struct ScanParams {
  const float* W[4];     // Wf,Wi,Wo,Wc  [2][H][H]
  const float* U[4];     // Uf,Ui,Uo,Uc  [2][H][H]
  const float* bias4[4]; // bf,bi,bo,bc  [2][H]
  const _Float16* xT;    // [L][B][H]
  _Float16* h1seq;       // [L][B][H]
  u64* hpub;             // [2][B][256][2]  {h2i,h2i+1,tag}
  float* dout;           // [B][L][H]
};

// x [B][L][H] fp32 -> xT [L][B][H] fp16
__global__ void prep_convert(const float* __restrict__ x, _Float16* __restrict__ xT) {
  size_t id = (size_t)blockIdx.x * blockDim.x + threadIdx.x;   // 4,194,304 total
  int k8 = (int)(id & (HH / 8 - 1)) * 8;
  size_t bt = id >> 7;                 // b*L + t
  int b = (int)(bt >> 11);
  int t = (int)(bt & (LL - 1));
  const float* src = x + (bt << 10) + k8;
  float4v v0 = *(const float4v*)(src);
  float4v v1 = *(const float4v*)(src + 4);
  half8 o;
  o[0] = (_Float16)v0[0]; o[1] = (_Float16)v0[1]; o[2] = (_Float16)v0[2]; o[3] = (_Float16)v0[3];
  o[4] = (_Float16)v1[0]; o[5] = (_Float16)v1[1]; o[6] = (_Float16)v1[2]; o[7] = (_Float16)v1[3];
  *(half8*)(xT + (((size_t)t * BB + b) << 10) + k8) = o;
}

// zero hpub (tags 0 == "initial h", h = 0)
__global__ void prep_init(u64* hpub) {
  int i = blockIdx.x * blockDim.x + threadIdx.x;
  if (i < 2 * BB * 256 * 2) hpub[i] = 0ull;
}

__device__ __forceinline__ float sigm(float x) { return 1.f / (1.f + __expf(-x)); }
__device__ __forceinline__ float tanh_fast(float x) { return 1.f - 2.f / (1.f + __expf(2.f * x)); }

__global__ __launch_bounds__(NTHR, 2) void lstm_scan(ScanParams p) {
  __shared__ _Float16 wlds[2][NR][KK];     // 131072 B, persistent weights
  __shared__ float acc_s[2][8][16][17];    // parity-double-buffered partials
  __shared__ float bias_s[2][NR];

  const int tid  = threadIdx.x;
  const int blk  = blockIdx.x;
  const int wv   = tid >> 6;
  const int lane = tid & 63;
  const int frow = lane & 15;   // A: batch row ; B: gate row
  const int kgrp = lane >> 4;

  // ---- one-time: weights fp32 -> fp16 into LDS, XOR-swizzled rows ----
  for (int idx = tid; idx < 2 * NR * KK; idx += NTHR) {
    int l = idx >> 15;
    int r = (idx >> 11) & (NR - 1);      // r = q*4 + jj
    int k = idx & (KK - 1);
    int q = r >> 2, jj = r & 3;
    int j = blk * NJ + jj;
    float v;
    if (k < HH) v = p.W[q][((size_t)l * HH + j) * HH + k];
    else        v = p.U[q][((size_t)l * HH + j) * HH + (k - HH)];
    unsigned bo = ((unsigned)(k * 2)) ^ ((unsigned)((r & 7) << 4));
    *(_Float16*)((char*)&wlds[l][r][0] + bo) = (_Float16)v;
  }
  if (tid < 2 * NR) {
    int l = tid >> 4, r = tid & 15;
    bias_s[l][r] = p.bias4[r >> 2][l * HH + blk * NJ + (r & 3)];
  }
  // wave 0: lane -> cell (b = lane>>2, jj = lane&3); c-state in register
  float cst = 0.f;
  __syncthreads();

  for (int s = 0; s < NSTEP; ++s) {
    const int l   = s >> 11;
    const int t   = s & (LL - 1);
    const int par = s & 1;

    // ---- phase A ----
    half8 aop[8];
    if (wv < 4) {
      // x-part: no wait -> overlaps the h-wave poll and wave-0 tail
      const _Float16* inp = (l == 0) ? p.xT : p.h1seq;
      const _Float16* ab = inp + (size_t)t * (BB * HH) + frow * HH + wv * 256 + kgrp * 8;
#pragma unroll
      for (int kk = 0; kk < 8; ++kk)
        aop[kk] = *(const half8*)(ab + kk * 32);
    } else {
      // Convergent tag poll: 32 u64 {h,h,tag} per lane. done-mask bit i set
      // once word i's tag == s; set words are never reloaded, so steady-state
      // retry traffic is only the straggler words (not 64 KB/block/round).
      const int hw = wv - 4;
      const u64* hp = p.hpub + (size_t)par * (BB * 256 * 2);
      const u32 want = (u32)s;
      const int qb = frow * 512 + hw * 128 + kgrp * 4;
      u64 q[32];
      u32 done = 0u;
      while (done != 0xFFFFFFFFu) {
#pragma unroll
        for (int kk = 0; kk < 8; ++kk) {
#pragma unroll
          for (int j = 0; j < 4; ++j) {
            const int i = kk * 4 + j;
            if (!((done >> i) & 1u))
              q[i] = __hip_atomic_load(hp + qb + kk * 16 + j,
                                       __ATOMIC_RELAXED, __HIP_MEMORY_SCOPE_AGENT);
          }
        }
        u32 nd = 0u;
#pragma unroll
        for (int i = 0; i < 32; ++i)
          nd |= (((u32)(q[i] >> 32) == want) ? 1u : 0u) << i;
        done = nd;
        if (done != 0xFFFFFFFFu) __builtin_amdgcn_s_sleep(1);
      }
#pragma unroll
      for (int kk = 0; kk < 8; ++kk) {
        union { u32 w[4]; half8 v; } u;
        u.w[0] = (u32)q[kk * 4 + 0]; u.w[1] = (u32)q[kk * 4 + 1];
        u.w[2] = (u32)q[kk * 4 + 2]; u.w[3] = (u32)q[kk * 4 + 3];
        aop[kk] = u.v;
      }
    }

    const int kw0 = wv * 256 + kgrp * 8;
    const char* wrow = (const char*)&wlds[l][frow][0];
    half8 bop[8];
#pragma unroll
    for (int kk = 0; kk < 8; ++kk) {
      unsigned bo = (unsigned)((kw0 + kk * 32) * 2) ^ ((unsigned)((frow & 7) << 4));
      bop[kk] = *(const half8*)(wrow + bo);
    }
    float4v a0 = {0.f, 0.f, 0.f, 0.f}, a1 = {0.f, 0.f, 0.f, 0.f};
#pragma unroll
    for (int kk = 0; kk < 8; kk += 2) {
      a0 = __builtin_amdgcn_mfma_f32_16x16x32_f16(aop[kk],     bop[kk],     a0, 0, 0, 0);
      a1 = __builtin_amdgcn_mfma_f32_16x16x32_f16(aop[kk + 1], bop[kk + 1], a1, 0, 0, 0);
    }
    a0 += a1;
#pragma unroll
    for (int v = 0; v < 4; ++v)
      acc_s[par][wv][kgrp * 4 + v][frow] = a0[v];   // row=batch=(lane>>4)*4+v, col=gaterow
    __syncthreads();   // the ONLY barrier per step

    // ---- phase B+C fused: wave 0 reduces, runs the cell, publishes ----
    if (wv == 0) {
      const int b = lane >> 2, jj = lane & 3;
      float g0 = bias_s[l][jj],      g1 = bias_s[l][4 + jj];
      float g2 = bias_s[l][8 + jj],  g3 = bias_s[l][12 + jj];
#pragma unroll
      for (int w = 0; w < 8; ++w) {
        g0 += acc_s[par][w][b][jj];
        g1 += acc_s[par][w][b][4 + jj];
        g2 += acc_s[par][w][b][8 + jj];
        g3 += acc_s[par][w][b][12 + jj];
      }
      float f = sigm(g0), i = sigm(g1), o = sigm(g2), cc = tanh_fast(g3);
      cst = f * cst + i * cc;
      float hf = o * tanh_fast(cst);

      union { _Float16 h; unsigned short us; } cv; cv.h = (_Float16)hf;
      u32 hu = cv.us;
      u32 v1 = __shfl_xor(hu, 1);
      u32 v2 = __shfl_xor(hu, 2);
      u32 v3 = __shfl_xor(v1, 2);
      float f1 = __shfl_xor(hf, 1);
      float f2 = __shfl_xor(hf, 2);
      float f3 = __shfl_xor(f1, 2);
      if (jj == 0) {
        u32 pair01 = hu | (v1 << 16);
        u32 pair23 = v2 | (v3 << 16);
        u64 tagw = ((u64)(u32)(s + 1)) << 32;
        u64* dst = p.hpub + (size_t)((s + 1) & 1) * (BB * 256 * 2) + b * 512 + blk * 2;
        __hip_atomic_store(dst + 0, (u64)pair01 | tagw, __ATOMIC_RELAXED, __HIP_MEMORY_SCOPE_AGENT);
        __hip_atomic_store(dst + 1, (u64)pair23 | tagw, __ATOMIC_RELAXED, __HIP_MEMORY_SCOPE_AGENT);
        if (l == 0) {
          u64 hq = (u64)pair01 | ((u64)pair23 << 32);
          __hip_atomic_store((u64*)(p.h1seq + ((size_t)t * BB + b) * HH + blk * 4), hq,
                             __ATOMIC_RELAXED, __HIP_MEMORY_SCOPE_AGENT);
        } else {
          float4v ov; ov[0] = hf; ov[1] = f1; ov[2] = f2; ov[3] = f3;
          *(float4v*)(p.dout + ((size_t)b * LL + t) * HH + blk * 4) = ov;
        }
      }
    }
    // no second barrier: waves 1-7 run step s+1 phase A into acc_s[par^1],
    // never touching acc_s[par] (read by wave 0) until after barrier s+1.
  }
}

extern "C" void kernel_launch(void* const* d_in, const int* in_sizes, int n_in,
                              void* d_out, int out_size, void* d_ws, size_t ws_size,
                              hipStream_t stream) {
  const float* x = (const float*)d_in[0];
  ScanParams sp;
  sp.W[0] = (const float*)d_in[1]; sp.U[0] = (const float*)d_in[2];   // f
  sp.W[1] = (const float*)d_in[3]; sp.U[1] = (const float*)d_in[4];   // i
  sp.W[2] = (const float*)d_in[5]; sp.U[2] = (const float*)d_in[6];   // o
  sp.W[3] = (const float*)d_in[7]; sp.U[3] = (const float*)d_in[8];   // c
  sp.bias4[0] = (const float*)d_in[9];  sp.bias4[1] = (const float*)d_in[10];
  sp.bias4[2] = (const float*)d_in[11]; sp.bias4[3] = (const float*)d_in[12];

  char* ws = (char*)d_ws;
  sp.xT    = (const _Float16*)(ws + WS_XT16);
  sp.h1seq = (_Float16*)(ws + WS_H1SEQ);
  sp.hpub  = (u64*)(ws + WS_HPUB);
  sp.dout  = (float*)d_out;

  prep_convert<<<16384, 256, 0, stream>>>(x, (_Float16*)(ws + WS_XT16));
  prep_init<<<64, 256, 0, stream>>>((u64*)(ws + WS_HPUB));
  lstm_scan<<<NBLK, NTHR, 0, stream>>>(sp);
}

// Round 9
// 26275.378 us; speedup vs baseline: 2.1224x; 1.7413x over previous
//
#include <hip/hip_runtime.h>

// ---------------------------------------------------------------------------
// 2-layer LSTM (B=16, L=2048, H=1024), one persistent scan kernel.
// Round-9: request-count minimization. Evidence (r2/r6/r8): step time scales
// with the NUMBER of coherence-path (sc1/atomic) requests (~5 ns each,
// chip-wide), not with hop latency. So:
//  * h data: 16B global_load_dwordx4 sc0 sc1 (plain, wide, L3-direct)
//    -> 0.52M requests/step vs round-8's 2.1M 8B atomics.
//  * h publish: 8B global_store_dwordx2 sc0 sc1 (write-through) +
//    s_waitcnt vmcnt(0) + one relaxed flag store per block (round-2-proven
//    ordering). No tags, no release wbl2, no acquire inv.
//  * poll: one flag per lane (wave polls exactly its 64 producers), packed
//    u32 flags -> ~4 coalesced line requests per wave per round.
// Topology unchanged: 256 blocks x 512 thr, weights in LDS (both layers),
// wave-0 cell with c-state in registers, single barrier, parity acc_s/hcur.
// ---------------------------------------------------------------------------

typedef _Float16 half8 __attribute__((ext_vector_type(8)));
typedef float    float4v __attribute__((ext_vector_type(4)));
typedef int      int4v  __attribute__((ext_vector_type(4)));
typedef unsigned long long u64;
typedef unsigned u32;

#define NBLK 256
#define NTHR 512
#define BB   16
#define LL   2048
#define HH   1024
#define KK   2048      // concat K (x-part 1024 + h-part 1024)
#define NJ   4         // h columns per block
#define NR   16        // gate rows per block (4 gates * NJ)
#define NSTEP 4096     // 2 layers * L

// ws layout (bytes)
#define WS_XT16   0u              // [L][B][H] fp16 : 64 MiB
#define WS_H1SEQ  67108864u       // [L][B][H] fp16 : 64 MiB
#define WS_HCUR   134217728u      // [2][B][H] fp16 : 64 KiB
#define WS_FLAGS  134283264u      // u32 flags[256] packed

struct ScanParams {
  const float* W[4];     // Wf,Wi,Wo,Wc  [2][H][H]
  const float* U[4];     // Uf,Ui,Uo,Uc  [2][H][H]
  const float* bias4[4]; // bf,bi,bo,bc  [2][H]
  const _Float16* xT;    // [L][B][H]
  _Float16* h1seq;       // [L][B][H]
  _Float16* hcur;        // [2][B][H]
  float* dout;           // [B][L][H]
  u32* flags;            // [256]
};

// x [B][L][H] fp32 -> xT [L][B][H] fp16
__global__ void prep_convert(const float* __restrict__ x, _Float16* __restrict__ xT) {
  size_t id = (size_t)blockIdx.x * blockDim.x + threadIdx.x;   // 4,194,304 total
  int k8 = (int)(id & (HH / 8 - 1)) * 8;
  size_t bt = id >> 7;                 // b*L + t
  int b = (int)(bt >> 11);
  int t = (int)(bt & (LL - 1));
  const float* src = x + (bt << 10) + k8;
  float4v v0 = *(const float4v*)(src);
  float4v v1 = *(const float4v*)(src + 4);
  half8 o;
  o[0] = (_Float16)v0[0]; o[1] = (_Float16)v0[1]; o[2] = (_Float16)v0[2]; o[3] = (_Float16)v0[3];
  o[4] = (_Float16)v1[0]; o[5] = (_Float16)v1[1]; o[6] = (_Float16)v1[2]; o[7] = (_Float16)v1[3];
  *(half8*)(xT + (((size_t)t * BB + b) << 10) + k8) = o;
}

__global__ void prep_init(_Float16* hcur, u32* flags) {
  int i = blockIdx.x * blockDim.x + threadIdx.x;
  if (i < 2 * BB * HH) hcur[i] = (_Float16)0.f;
  if (i < 256) flags[i] = 0u;
}

__device__ __forceinline__ float sigm(float x) { return 1.f / (1.f + __expf(-x)); }
__device__ __forceinline__ float tanh_fast(float x) { return 1.f - 2.f / (1.f + __expf(2.f * x)); }

// 16B coherent load: bypasses (possibly stale) L1/L2, served at L3.
__device__ __forceinline__ int4v load16_coh(const void* p) {
  int4v r;
  asm volatile("global_load_dwordx4 %0, %1, off sc0 sc1"
               : "=v"(r) : "v"(p) : "memory");
  return r;
}
// 8B coherent (write-through) store.
__device__ __forceinline__ void store8_coh(void* p, u64 v) {
  asm volatile("global_store_dwordx2 %0, %1, off sc0 sc1"
               :: "v"(p), "v"(v) : "memory");
}

__global__ __launch_bounds__(NTHR, 2) void lstm_scan(ScanParams p) {
  __shared__ _Float16 wlds[2][NR][KK];     // 131072 B, persistent weights
  __shared__ float acc_s[2][8][16][17];    // parity-double-buffered partials
  __shared__ float bias_s[2][NR];

  const int tid  = threadIdx.x;
  const int blk  = blockIdx.x;
  const int wv   = tid >> 6;
  const int lane = tid & 63;
  const int frow = lane & 15;   // A: batch row ; B: gate row
  const int kgrp = lane >> 4;

  // ---- one-time: weights fp32 -> fp16 into LDS, XOR-swizzled rows ----
  for (int idx = tid; idx < 2 * NR * KK; idx += NTHR) {
    int l = idx >> 15;
    int r = (idx >> 11) & (NR - 1);      // r = q*4 + jj
    int k = idx & (KK - 1);
    int q = r >> 2, jj = r & 3;
    int j = blk * NJ + jj;
    float v;
    if (k < HH) v = p.W[q][((size_t)l * HH + j) * HH + k];
    else        v = p.U[q][((size_t)l * HH + j) * HH + (k - HH)];
    unsigned bo = ((unsigned)(k * 2)) ^ ((unsigned)((r & 7) << 4));
    *(_Float16*)((char*)&wlds[l][r][0] + bo) = (_Float16)v;
  }
  if (tid < 2 * NR) {
    int l = tid >> 4, r = tid & 15;
    bias_s[l][r] = p.bias4[r >> 2][l * HH + blk * NJ + (r & 3)];
  }
  // wave 0: lane -> cell (b = lane>>2, jj = lane&3); c-state in register
  float cst = 0.f;
  __syncthreads();

  for (int s = 0; s < NSTEP; ++s) {
    const int l   = s >> 11;
    const int t   = s & (LL - 1);
    const int par = s & 1;

    // ---- phase A ----
    half8 aop[8];
    if (wv < 4) {
      // x-part: plain cached loads; no dependency on the grid exchange
      const _Float16* inp = (l == 0) ? p.xT : p.h1seq;
      const _Float16* ab = inp + (size_t)t * (BB * HH) + frow * HH + wv * 256 + kgrp * 8;
#pragma unroll
      for (int kk = 0; kk < 8; ++kk)
        aop[kk] = *(const half8*)(ab + kk * 32);
    } else {
      // poll: one flag per lane (this wave's 64 producer blocks)
      const int hw = wv - 4;
      {
        u32* fl = p.flags + hw * 64 + lane;
        const u32 target = (u32)s;
        while (__hip_atomic_load(fl, __ATOMIC_RELAXED, __HIP_MEMORY_SCOPE_AGENT) < target)
          __builtin_amdgcn_s_sleep(1);
      }
      __builtin_amdgcn_sched_barrier(0);
      // h data: 16B coherent loads (issue-after-poll by in-order VMEM issue)
      const _Float16* hb = p.hcur + (size_t)par * (BB * HH) + frow * HH + hw * 256 + kgrp * 8;
      int4v raw[8];
#pragma unroll
      for (int kk = 0; kk < 8; ++kk)
        raw[kk] = load16_coh(hb + kk * 32);
      asm volatile("s_waitcnt vmcnt(0)" ::: "memory");
      __builtin_amdgcn_sched_barrier(0);
#pragma unroll
      for (int kk = 0; kk < 8; ++kk) {
        union { int4v w; half8 v; } u;
        u.w = raw[kk];
        aop[kk] = u.v;
      }
    }

    const int kw0 = wv * 256 + kgrp * 8;
    const char* wrow = (const char*)&wlds[l][frow][0];
    half8 bop[8];
#pragma unroll
    for (int kk = 0; kk < 8; ++kk) {
      unsigned bo = (unsigned)((kw0 + kk * 32) * 2) ^ ((unsigned)((frow & 7) << 4));
      bop[kk] = *(const half8*)(wrow + bo);
    }
    float4v a0 = {0.f, 0.f, 0.f, 0.f}, a1 = {0.f, 0.f, 0.f, 0.f};
#pragma unroll
    for (int kk = 0; kk < 8; kk += 2) {
      a0 = __builtin_amdgcn_mfma_f32_16x16x32_f16(aop[kk],     bop[kk],     a0, 0, 0, 0);
      a1 = __builtin_amdgcn_mfma_f32_16x16x32_f16(aop[kk + 1], bop[kk + 1], a1, 0, 0, 0);
    }
    a0 += a1;
#pragma unroll
    for (int v = 0; v < 4; ++v)
      acc_s[par][wv][kgrp * 4 + v][frow] = a0[v];   // row=batch=(lane>>4)*4+v, col=gaterow
    __syncthreads();   // the ONLY barrier per step

    // ---- phase B+C fused: wave 0 reduces, runs the cell, publishes ----
    if (wv == 0) {
      const int b = lane >> 2, jj = lane & 3;
      float g0 = bias_s[l][jj],      g1 = bias_s[l][4 + jj];
      float g2 = bias_s[l][8 + jj],  g3 = bias_s[l][12 + jj];
#pragma unroll
      for (int w = 0; w < 8; ++w) {
        g0 += acc_s[par][w][b][jj];
        g1 += acc_s[par][w][b][4 + jj];
        g2 += acc_s[par][w][b][8 + jj];
        g3 += acc_s[par][w][b][12 + jj];
      }
      float f = sigm(g0), i = sigm(g1), o = sigm(g2), cc = tanh_fast(g3);
      cst = f * cst + i * cc;
      float hf = o * tanh_fast(cst);

      union { _Float16 h; unsigned short us; } cv; cv.h = (_Float16)hf;
      u32 hu = cv.us;
      u32 v1 = __shfl_xor(hu, 1);
      u32 v2 = __shfl_xor(hu, 2);
      u32 v3 = __shfl_xor(v1, 2);
      float f1 = __shfl_xor(hf, 1);
      float f2 = __shfl_xor(hf, 2);
      float f3 = __shfl_xor(f1, 2);
      if (jj == 0) {
        u32 pair01 = hu | (v1 << 16);
        u32 pair23 = v2 | (v3 << 16);
        u64 hq = (u64)pair01 | ((u64)pair23 << 32);
        // publish h for step s+1 consumers (parity buffer (s+1)&1)
        store8_coh(p.hcur + (size_t)((s + 1) & 1) * (BB * HH) + b * HH + blk * 4, hq);
        if (l == 0) {
          store8_coh(p.h1seq + ((size_t)t * BB + b) * HH + blk * 4, hq);
        } else {
          float4v ov; ov[0] = hf; ov[1] = f1; ov[2] = f2; ov[3] = f3;
          *(float4v*)(p.dout + ((size_t)b * LL + t) * HH + blk * 4) = ov;
        }
      }
      // drain this wave's stores to the coherence point, then raise the flag
      asm volatile("s_waitcnt vmcnt(0)" ::: "memory");
      if (lane == 0)
        __hip_atomic_store(&p.flags[blk], (u32)(s + 1), __ATOMIC_RELAXED, __HIP_MEMORY_SCOPE_AGENT);
    }
    // no second barrier: waves 1-7 run step s+1 phase A into acc_s[par^1],
    // never touching acc_s[par] (read by wave 0) until after barrier s+1.
  }
}

extern "C" void kernel_launch(void* const* d_in, const int* in_sizes, int n_in,
                              void* d_out, int out_size, void* d_ws, size_t ws_size,
                              hipStream_t stream) {
  const float* x = (const float*)d_in[0];
  ScanParams sp;
  sp.W[0] = (const float*)d_in[1]; sp.U[0] = (const float*)d_in[2];   // f
  sp.W[1] = (const float*)d_in[3]; sp.U[1] = (const float*)d_in[4];   // i
  sp.W[2] = (const float*)d_in[5]; sp.U[2] = (const float*)d_in[6];   // o
  sp.W[3] = (const float*)d_in[7]; sp.U[3] = (const float*)d_in[8];   // c
  sp.bias4[0] = (const float*)d_in[9];  sp.bias4[1] = (const float*)d_in[10];
  sp.bias4[2] = (const float*)d_in[11]; sp.bias4[3] = (const float*)d_in[12];

  char* ws = (char*)d_ws;
  sp.xT    = (const _Float16*)(ws + WS_XT16);
  sp.h1seq = (_Float16*)(ws + WS_H1SEQ);
  sp.hcur  = (_Float16*)(ws + WS_HCUR);
  sp.flags = (u32*)(ws + WS_FLAGS);
  sp.dout  = (float*)d_out;

  prep_convert<<<16384, 256, 0, stream>>>(x, (_Float16*)(ws + WS_XT16));
  prep_init<<<128, 256, 0, stream>>>((_Float16*)(ws + WS_HCUR), (u32*)(ws + WS_FLAGS));
  lstm_scan<<<NBLK, NTHR, 0, stream>>>(sp);
}